// Round 15
// baseline (11438.654 us; speedup 1.0000x reference)
//
#include <hip/hip_runtime.h>
#include <math.h>

// ---------------------------------------------------------------------------
// PTB LN-LSTM stack: B=128, T=100, E=128, F=700, S=400, V=10000.
// Round 15 (on r14's write-through + single-inv barrier):
//   (1) single-hop barrier: all blocks poll all 256 flags RELAXED (no go-hop)
//   (2) buffer_inv issued by a NON-polling wave (tid 256) -> fully overlapped
//   (3) LDS weight-tile chunk swizzle (chunk ^= (col>>1)&3): 8-way -> 2-way
//       bank aliasing on ds_read_b128 (2-way is free)
// All stores remain write-through coherent (sc0 sc1); all 6 barriers keep
// their single inv (coherence invariant re-derived: every phase's reader set
// is stale-cached by the previous phase's readers).
// Arithmetic untouched -> absmax must stay exactly 0.03125.
// ---------------------------------------------------------------------------

#define B_ 128
#define T_ 100
#define E_ 128
#define F_ 700
#define S_ 400
#define V_ 10000

#define FP_ 704    // F padded
#define SP_ 416    // S padded
#define G_  256    // mega blocks
#define TPB_ 512   // threads per mega block (8 waves)

#define W0_TILE_B 45056    // 22 kt * 2048
#define KW_TILE_B 71680    // 35 kt * 2048
#define LDS_BYTES 143360   // max: two KW tiles

using v8s = __attribute__((ext_vector_type(8))) short;
using v4f = __attribute__((ext_vector_type(4))) float;
typedef unsigned short u16;

#define NTL(p)    __builtin_nontemporal_load((p))

// Write-through device-coherent stores (never dirty L2).
__device__ __forceinline__ void stcohf(float* p, float v) {
    asm volatile("global_store_dword %0, %1, off sc0 sc1" :: "v"(p), "v"(v) : "memory");
}
__device__ __forceinline__ void stcohs(u16* p, u16 v) {
    unsigned w = v;
    asm volatile("global_store_short %0, %1, off sc0 sc1" :: "v"(p), "v"(w) : "memory");
}

__device__ __forceinline__ u16 f2bf(float x) {
    unsigned int u = __float_as_uint(x);
    u += 0x7FFFu + ((u >> 16) & 1u);
    return (u16)(u >> 16);
}
__device__ __forceinline__ float bf2f(u16 h) {
    return __uint_as_float(((unsigned int)h) << 16);
}
__device__ __forceinline__ void split3f(float x, u16& h, u16& m, u16& l) {
    h = f2bf(x); float r  = x - bf2f(h);
    m = f2bf(r); float r2 = r - bf2f(m);
    l = f2bf(r2);
}
__device__ __forceinline__ float sigm(float x) { return 1.0f / (1.0f + expf(-x)); }

// ---------------------------------------------------------------------------
// Single-hop grid barrier:
//   waves drain write-through stores (vmcnt 0) -> syncthreads ->
//   tid0: RELAXED flag store | tid256: ONE buffer_inv (non-polling wave,
//   overlaps the wait) | tid<256: poll one flag each RELAXED -> syncthreads.
// ---------------------------------------------------------------------------
__device__ __forceinline__ void gbar(unsigned* flags, unsigned target) {
    asm volatile("s_waitcnt vmcnt(0)" ::: "memory");
    __syncthreads();
    if (threadIdx.x == 0)
        __hip_atomic_store(flags + (size_t)blockIdx.x * 16, target,
                           __ATOMIC_RELAXED, __HIP_MEMORY_SCOPE_AGENT);
    if (threadIdx.x == 256)
        asm volatile("buffer_inv sc0 sc1\n\ts_waitcnt vmcnt(0)" ::: "memory");
    if (threadIdx.x < G_) {
        const unsigned* f = flags + (size_t)threadIdx.x * 16;
        while (__hip_atomic_load(f, __ATOMIC_RELAXED, __HIP_MEMORY_SCOPE_AGENT) < target)
            __builtin_amdgcn_s_sleep(1);
    }
    __syncthreads();
}

// ---------------------------------------------------------------------------
// Transpose+split kernels (r5-proven; full-coverage writes).
// ---------------------------------------------------------------------------
__global__ __launch_bounds__(256) void wtrans3(
    const float* __restrict__ W, int K, int N,
    u16* __restrict__ WtH, u16* __restrict__ WtM, u16* __restrict__ WtL,
    int Kp, int K1, int K1pad)
{
    __shared__ float t[32][33];
    const int c0 = blockIdx.x * 32, kp0 = blockIdx.y * 32;
    const int tx = threadIdx.x & 31, ty = threadIdx.x >> 5;
    #pragma unroll
    for (int i = 0; i < 4; ++i) {
        int kpos = kp0 + ty + i * 8, c = c0 + tx;
        int k = (kpos < K1) ? kpos : (kpos >= K1pad ? K1 + (kpos - K1pad) : -1);
        t[ty + i * 8][tx] = (k >= 0 && k < K && c < N) ? W[(size_t)k * N + c] : 0.f;
    }
    __syncthreads();
    #pragma unroll
    for (int i = 0; i < 4; ++i) {
        int r = c0 + ty + i * 8;
        u16 h, m, l;
        split3f(t[tx][ty + i * 8], h, m, l);
        size_t idx = (size_t)r * Kp + kp0 + tx;
        WtH[idx] = h; WtM[idx] = m; WtL[idx] = l;
    }
}

__global__ __launch_bounds__(256) void wtrans(
    const float* __restrict__ W, int K, int N,
    u16* __restrict__ Wt, int Kpad)
{
    __shared__ float t[32][33];
    const int c0 = blockIdx.x * 32, k0 = blockIdx.y * 32;
    const int tx = threadIdx.x & 31, ty = threadIdx.x >> 5;
    #pragma unroll
    for (int i = 0; i < 4; ++i) {
        int k = k0 + ty + i * 8, c = c0 + tx;
        t[ty + i * 8][tx] = (k < K && c < N) ? W[(size_t)k * N + c] : 0.f;
    }
    __syncthreads();
    #pragma unroll
    for (int i = 0; i < 4; ++i) {
        int r = c0 + ty + i * 8;
        Wt[(size_t)r * Kpad + k0 + tx] = f2bf(t[tx][ty + i * 8]);
    }
}

// ---------------------------------------------------------------------------
// zx precompute (r7-proven).
// ---------------------------------------------------------------------------
__global__ __launch_bounds__(512, 1) void zxpre(
    const float* __restrict__ inputs,
    const u16* __restrict__ WH, const u16* __restrict__ WM,
    const u16* __restrict__ WL, const float* __restrict__ b0,
    float* __restrict__ zx)
{
    const int lane = threadIdx.x & 63, wid = threadIdx.x >> 6;
    const int lo = lane & 15, hi = lane >> 4;
    const int ntiles = 175 * 100;
    for (int i = blockIdx.x * 8 + wid; i < ntiles; i += gridDim.x * 8) {
        const int t = i / 175, ct = i % 175;
        v4f acc[8];
        #pragma unroll
        for (int m = 0; m < 8; ++m) acc[m] = (v4f)0.f;
        const size_t bb = (size_t)(ct * 16 + lo) * 832 + hi * 8;
        for (int kt = 0; kt < 4; ++kt) {
            const size_t bo = bb + kt * 32;
            v8s bh = *(const v8s*)(WH + bo);
            v8s bm = *(const v8s*)(WM + bo);
            v8s bl = *(const v8s*)(WL + bo);
            #pragma unroll
            for (int m = 0; m < 8; ++m) {
                const float* p = inputs + (size_t)(m * 16 + lo) * (T_ * E_)
                               + (size_t)t * E_ + kt * 32 + hi * 8;
                float v0[8];
                *(float4*)(v0)     = *(const float4*)(p);
                *(float4*)(v0 + 4) = *(const float4*)(p + 4);
                v8s ah, am, al;
                #pragma unroll
                for (int j = 0; j < 8; ++j) {
                    u16 H, M, L; split3f(v0[j], H, M, L);
                    ah[j] = (short)H; am[j] = (short)M; al[j] = (short)L;
                }
                acc[m] = __builtin_amdgcn_mfma_f32_16x16x32_bf16(ah, bh, acc[m], 0, 0, 0);
                acc[m] = __builtin_amdgcn_mfma_f32_16x16x32_bf16(ah, bm, acc[m], 0, 0, 0);
                acc[m] = __builtin_amdgcn_mfma_f32_16x16x32_bf16(am, bh, acc[m], 0, 0, 0);
                acc[m] = __builtin_amdgcn_mfma_f32_16x16x32_bf16(ah, bl, acc[m], 0, 0, 0);
                acc[m] = __builtin_amdgcn_mfma_f32_16x16x32_bf16(al, bh, acc[m], 0, 0, 0);
                acc[m] = __builtin_amdgcn_mfma_f32_16x16x32_bf16(am, bm, acc[m], 0, 0, 0);
            }
        }
        const int col = ct * 16 + lo;
        const float bb0 = b0[col];
        #pragma unroll
        for (int m = 0; m < 8; ++m)
            #pragma unroll
            for (int r = 0; r < 4; ++r) {
                int row = m * 16 + hi * 4 + r;
                zx[((size_t)t * B_ + row) * 2800 + col] = acc[m][r] + bb0;
            }
    }
}

// ---------------------------------------------------------------------------
// LDS weight-tile fill. Chunk swizzle: chunk c of col stored at
// kt*2048 + col*64 + ((c ^ ((col>>1)&3)) * 16)   (+1024 for M plane).
// Spreads the 16 same-chunk lanes over 4 bank-groups -> 2-way max (free).
// ---------------------------------------------------------------------------
__device__ void fill_tile(char* dst, const u16* __restrict__ H,
                          const u16* __restrict__ M, int Kp, int gcol0, int NT)
{
    const int n = 16 * NT * 4;
    for (int idx = threadIdx.x; idx < n; idx += TPB_) {
        const int c   = idx & 3;
        const int kt  = (idx >> 2) % NT;
        const int col = (idx >> 2) / NT;
        const size_t g = (size_t)(gcol0 + col) * Kp + kt * 32 + c * 8;
        const int o = kt * 2048 + col * 64 + ((c ^ ((col >> 1) & 3)) * 16);
        *(v8s*)(dst + o)        = *(const v8s*)(H + g);
        *(v8s*)(dst + o + 1024) = *(const v8s*)(M + g);
    }
}

// ---------------------------------------------------------------------------
// GEMM phase (r13 structure: depth-3 A/L ring, B H/M from swizzled LDS).
// MFMA order per acc identical to r5-r14.
// ---------------------------------------------------------------------------
__device__ void gemm_lds(
    const char* lt, int NT,
    const u16* __restrict__ A1H, const u16* __restrict__ A1M,
    const u16* __restrict__ A1L, int lda1, int K1pad,
    const u16* __restrict__ A2H, const u16* __restrict__ A2M,
    const u16* __restrict__ A2L, int lda2,
    const u16* __restrict__ WL, int KpL, int col0,
    const float* __restrict__ bias, const float* __restrict__ zadd,
    float* __restrict__ z, int N)
{
    const int lane = threadIdx.x & 63;
    const int lo = lane & 15, hi = lane >> 4;
    const int r0 = (threadIdx.x >> 6) * 16;
    v4f acc = (v4f)0.f;
    const u16* blp = WL + (size_t)(col0 + lo) * KpL + hi * 8;
    const size_t arow = (size_t)(r0 + lo);
    const int csw = (hi ^ ((lo >> 1) & 3)) << 4;   // swizzled chunk offset

    v8s aH[3], aM[3], aL[3], bL[3];
    #pragma unroll
    for (int s = 0; s < 3; ++s) {
        const int kb2 = s * 32;
        const bool s1 = kb2 < K1pad;
        const size_t ao = arow * (s1 ? lda1 : lda2)
                        + (s1 ? kb2 : kb2 - K1pad) + hi * 8;
        aH[s] = *(const v8s*)((s1 ? A1H : A2H) + ao);
        aM[s] = *(const v8s*)((s1 ? A1M : A2M) + ao);
        aL[s] = *(const v8s*)((s1 ? A1L : A2L) + ao);
        bL[s] = *(const v8s*)(blp + kb2);
    }

    for (int kt0 = 0; kt0 < NT; kt0 += 3) {
        #pragma unroll
        for (int j = 0; j < 3; ++j) {
            const int kt = kt0 + j;
            if (kt < NT) {
                const int lb = kt * 2048 + lo * 64 + csw;
                v8s bh = *(const v8s*)(lt + lb);
                v8s bm = *(const v8s*)(lt + lb + 1024);
                acc = __builtin_amdgcn_mfma_f32_16x16x32_bf16(aH[j], bh,    acc, 0, 0, 0);
                acc = __builtin_amdgcn_mfma_f32_16x16x32_bf16(aH[j], bm,    acc, 0, 0, 0);
                acc = __builtin_amdgcn_mfma_f32_16x16x32_bf16(aM[j], bh,    acc, 0, 0, 0);
                acc = __builtin_amdgcn_mfma_f32_16x16x32_bf16(aH[j], bL[j], acc, 0, 0, 0);
                acc = __builtin_amdgcn_mfma_f32_16x16x32_bf16(aL[j], bh,    acc, 0, 0, 0);
                acc = __builtin_amdgcn_mfma_f32_16x16x32_bf16(aM[j], bm,    acc, 0, 0, 0);
                const int kn = kt + 3;
                if (kn < NT) {
                    const int kb2 = kn * 32;
                    const bool s1 = kb2 < K1pad;
                    const size_t ao = arow * (s1 ? lda1 : lda2)
                                    + (s1 ? kb2 : kb2 - K1pad) + hi * 8;
                    aH[j] = *(const v8s*)((s1 ? A1H : A2H) + ao);
                    aM[j] = *(const v8s*)((s1 ? A1M : A2M) + ao);
                    aL[j] = *(const v8s*)((s1 ? A1L : A2L) + ao);
                    bL[j] = *(const v8s*)(blp + kb2);
                }
            }
        }
    }

    const int col = col0 + lo;
    if (zadd) {
        #pragma unroll
        for (int r = 0; r < 4; ++r) {
            int row = r0 + hi * 4 + r;
            float za = NTL(&zadd[(size_t)row * N + col]);
            stcohf(&z[(size_t)row * N + col], acc[r] + za);
        }
    } else {
        const float bv = bias[col];
        #pragma unroll
        for (int r = 0; r < 4; ++r) {
            int row = r0 + hi * 4 + r;
            stcohf(&z[(size_t)row * N + col], acc[r] + bv);
        }
    }
}

// ---------------------------------------------------------------------------
// Batched block reduction (r13-proven; order identical to r5-r14).
// ---------------------------------------------------------------------------
template <int NV>
__device__ __forceinline__ void blockSumN(float* v, float* red) {
    const int w = threadIdx.x >> 6, lane = threadIdx.x & 63;
    #pragma unroll
    for (int k = 0; k < NV; ++k) {
        float x = v[k];
        #pragma unroll
        for (int off = 32; off > 0; off >>= 1) x += __shfl_down(x, off, 64);
        v[k] = x;
    }
    __syncthreads();
    if (lane == 0) {
        #pragma unroll
        for (int k = 0; k < NV; ++k) red[k * 8 + w] = v[k];
    }
    __syncthreads();
    #pragma unroll
    for (int k = 0; k < NV; ++k) {
        float r = 0.f;
        #pragma unroll
        for (int j = 0; j < 8; ++j) r += red[k * 8 + j];
        v[k] = r;
    }
    __syncthreads();
}

// ---------------------------------------------------------------------------
// Pointwise phase (r14: all stores write-through coherent).
// ---------------------------------------------------------------------------
template <int FF>
__device__ void pw_phase(const float* __restrict__ z,
    const float* __restrict__ gg, const float* __restrict__ bg,
    const float* __restrict__ gc, const float* __restrict__ bc,
    float* __restrict__ h, float* __restrict__ c,
    u16* __restrict__ hpH, u16* __restrict__ hpM, u16* __restrict__ hpL,
    int hstride, u16* __restrict__ hist, int t, float* red)
{
    const int tid = threadIdx.x;
    constexpr int NU = (FF + TPB_ - 1) / TPB_;
    for (int b = blockIdx.x; b < B_; b += G_) {
        const float* zr = z + (size_t)b * 4 * FF;
        float* hr = h + (size_t)b * FF;
        float* cr = c + (size_t)b * FF;

        float sv[8] = {0, 0, 0, 0, 0, 0, 0, 0};
        #pragma unroll
        for (int i = 0; i < NU; ++i) {
            int u = tid + i * TPB_;
            if (u < FF) {
                #pragma unroll
                for (int g = 0; g < 4; ++g) {
                    float v = NTL(&zr[g * FF + u]);
                    sv[g] += v; sv[4 + g] += v * v;
                }
            }
        }
        blockSumN<8>(sv, red);
        float mu[4], rs[4];
        #pragma unroll
        for (int g = 0; g < 4; ++g) {
            mu[g] = sv[g] / FF;
            rs[g] = rsqrtf(sv[4 + g] / FF - mu[g] * mu[g] + 1e-5f);
        }

        float nc[NU], og[NU], ho[NU], co[NU];
        float cv[2] = {0, 0};
        #pragma unroll
        for (int i = 0; i < NU; ++i) {
            int u = tid + i * TPB_;
            if (u < FF) {
                float zi = (NTL(&zr[u])          - mu[0]) * rs[0] * gg[u]          + bg[u];
                float zj = (NTL(&zr[FF + u])     - mu[1]) * rs[1] * gg[FF + u]     + bg[FF + u];
                float zf = (NTL(&zr[2 * FF + u]) - mu[2]) * rs[2] * gg[2 * FF + u] + bg[2 * FF + u];
                float zo = (NTL(&zr[3 * FF + u]) - mu[3]) * rs[3] * gg[3 * FF + u] + bg[3 * FF + u];
                float cold = cr[u];
                float ncv = cold * sigm(zf + 1.0f) + sigm(zi) * tanhf(zj);
                nc[i] = ncv; og[i] = sigm(zo); co[i] = cold; ho[i] = hr[u];
                cv[0] += ncv; cv[1] += ncv * ncv;
            } else { nc[i] = 0.f; og[i] = 0.f; co[i] = 0.f; ho[i] = 0.f; }
        }
        blockSumN<2>(cv, red);
        float muc = cv[0] / FF;
        float rsc = rsqrtf(cv[1] / FF - muc * muc + 1e-5f);

        #pragma unroll
        for (int i = 0; i < NU; ++i) {
            int u = tid + i * TPB_;
            if (u < FF) {
                float nh = tanhf((nc[i] - muc) * rsc * gc[u] + bc[u]) * og[i];
                float hout = 0.9f * nh + 0.1f * ho[i];
                float cout = 0.5f * nc[i] + 0.5f * co[i];
                stcohf(&hr[u], hout);
                stcohf(&cr[u], cout);
                u16 H, M, L;
                split3f(hout, H, M, L);
                size_t po = (size_t)b * hstride + u;
                stcohs(&hpH[po], H); stcohs(&hpM[po], M); stcohs(&hpL[po], L);
                if (hist) stcohs(&hist[((size_t)b * T_ + t) * FP_ + u], H);
            }
        }
        if (hist && tid < FP_ - FF)
            stcohs(&hist[((size_t)b * T_ + t) * FP_ + FF + tid], (u16)0);
    }
}

// ---------------------------------------------------------------------------
// Mega: LDS-fill -> 100 x (GEMM0|PW0|GEMMS|PWS|GEMM1|PW1) -> tail.
// Tile map: b<=155:{W0[b],W1[b]} 156..174:{W0[b],WS[b-156]}
//           175..193:{WS[b-156],W1[156+b-175]} 194..255:{WS[b-156]}
// ---------------------------------------------------------------------------
__global__ __launch_bounds__(TPB_) void mega(
    const float* __restrict__ b0, const float* __restrict__ g0,
    const float* __restrict__ bg0, const float* __restrict__ gc0,
    const float* __restrict__ bc0,
    const float* __restrict__ b1, const float* __restrict__ g1,
    const float* __restrict__ bg1, const float* __restrict__ gc1,
    const float* __restrict__ bc1,
    const float* __restrict__ bS, const float* __restrict__ gS,
    const float* __restrict__ bgS, const float* __restrict__ gcS,
    const float* __restrict__ bcS,
    const float* __restrict__ zx,
    float* fh, float* fc, float* sh, float* sc, float* z, u16* hist,
    u16* fhH, u16* fhM, u16* fhL, u16* shH, u16* shM, u16* shL,
    u16* W0H, u16* W0M, u16* W0L, u16* WSH, u16* WSM, u16* WSL,
    u16* W1H, u16* W1M, u16* W1L,
    float* outTail, unsigned* flags)
{
    extern __shared__ char lds[];
    __shared__ float red[64];
    const int b = blockIdx.x;
    const int gtid = blockIdx.x * TPB_ + threadIdx.x;
    unsigned tgt = 0;

    // one-time LDS weight fill (block-local)
    if (b <= 174) {
        fill_tile(lds, W0H + 128, W0M + 128, 832, b * 16, 22);
        if (b <= 155) fill_tile(lds + W0_TILE_B, W1H, W1M, 1120, b * 16, 35);
        else          fill_tile(lds + W0_TILE_B, WSH, WSM, 1120, (b - 156) * 16, 35);
    } else {
        fill_tile(lds, WSH, WSM, 1120, (b - 156) * 16, 35);
        if (b <= 193)
            fill_tile(lds + KW_TILE_B, W1H, W1M, 1120, (156 + b - 175) * 16, 35);
    }
    __syncthreads();

    for (int t = 0; t < T_; ++t) {
        if (b <= 174)
            gemm_lds(lds, 22,
                     fhH, fhM, fhL, FP_, FP_, fhH, fhM, fhL, FP_,
                     W0L + 128, 832, b * 16,
                     nullptr, zx + (size_t)t * B_ * 2800, z, 2800);
        gbar(flags, ++tgt);
        pw_phase<F_>(z, g0, bg0, gc0, bc0, fh, fc, fhH, fhM, fhL, FP_, nullptr, 0, red);
        gbar(flags, ++tgt);
        if (b >= 156)
            gemm_lds(lds + (b <= 174 ? W0_TILE_B : 0), 35,
                     fhH, fhM, fhL, FP_, FP_, shH, shM, shL, SP_,
                     WSL, 1120, (b - 156) * 16,
                     bS, nullptr, z, 1600);
        gbar(flags, ++tgt);
        pw_phase<S_>(z, gS, bgS, gcS, bcS, sh, sc, shH, shM, shL, SP_, nullptr, 0, red);
        gbar(flags, ++tgt);
        if (b <= 155)
            gemm_lds(lds + W0_TILE_B, 35,
                     shH, shM, shL, SP_, SP_, fhH, fhM, fhL, FP_,
                     W1L, 1120, b * 16, b1, nullptr, z, 2800);
        else if (b >= 175 && b <= 193)
            gemm_lds(lds + KW_TILE_B, 35,
                     shH, shM, shL, SP_, SP_, fhH, fhM, fhL, FP_,
                     W1L, 1120, (156 + b - 175) * 16, b1, nullptr, z, 2800);
        gbar(flags, ++tgt);
        pw_phase<F_>(z, g1, bg1, gc1, bc1, fh, fc, fhH, fhM, fhL, FP_, hist, t, red);
        gbar(flags, ++tgt);
    }

    const int NF = B_ * F_, NS = B_ * S_;
    for (int i = gtid; i < 2 * NF + 2 * NS; i += G_ * TPB_) {
        float v = (i < NF) ? fh[i] : (i < 2 * NF) ? fc[i - NF]
                : (i < 2 * NF + NS) ? sh[i - 2 * NF] : sc[i - 2 * NF - NS];
        stcohf(&outTail[i], v);
    }
}

// ---------------------------------------------------------------------------
// Output projection (r5-proven).
// ---------------------------------------------------------------------------
__global__ __launch_bounds__(512) void ogemm(
    const u16* __restrict__ A, const u16* __restrict__ Bt,
    const float* __restrict__ bias, float* __restrict__ C)
{
    const int N = V_;
    const int tid = threadIdx.x, lane = tid & 63, wid = tid >> 6;
    const int wm = wid >> 1, wn = wid & 1;
    const int row0 = blockIdx.y * 256 + wm * 64;
    const int col0 = blockIdx.x * 128 + wn * 64;
    const int lo = lane & 15, hi = lane >> 4;
    const int NT = FP_ / 32;

    v4f acc[4][4];
    #pragma unroll
    for (int i = 0; i < 4; ++i)
        #pragma unroll
        for (int j = 0; j < 4; ++j) acc[i][j] = (v4f)0.f;

    for (int kt = 0; kt < NT; ++kt) {
        const int kb = kt * 32 + hi * 8;
        v8s a[4], bfr[4];
        #pragma unroll
        for (int i = 0; i < 4; ++i) {
            a[i]   = *(const v8s*)(A  + (size_t)(row0 + i * 16 + lo) * FP_ + kb);
            bfr[i] = *(const v8s*)(Bt + (size_t)(col0 + i * 16 + lo) * FP_ + kb);
        }
        #pragma unroll
        for (int mf = 0; mf < 4; ++mf)
            #pragma unroll
            for (int nf = 0; nf < 4; ++nf)
                acc[mf][nf] = __builtin_amdgcn_mfma_f32_16x16x32_bf16(a[mf], bfr[nf], acc[mf][nf], 0, 0, 0);
    }

    #pragma unroll
    for (int mf = 0; mf < 4; ++mf) {
        #pragma unroll
        for (int nf = 0; nf < 4; ++nf) {
            int col = col0 + nf * 16 + lo;
            if (col < N) {
                float bb = bias[col];
                #pragma unroll
                for (int r = 0; r < 4; ++r) {
                    int row = row0 + mf * 16 + hi * 4 + r;
                    C[(size_t)row * N + col] = acc[mf][nf][r] + bb;
                }
            }
        }
    }
}

extern "C" void kernel_launch(void* const* d_in, const int* in_sizes, int n_in,
                              void* d_out, int out_size, void* d_ws, size_t ws_size,
                              hipStream_t stream) {
    const float* inputs = (const float*)d_in[0];
    const float* W0   = (const float*)d_in[1];
    const float* b0   = (const float*)d_in[2];
    const float* g0   = (const float*)d_in[3];
    const float* bg0  = (const float*)d_in[4];
    const float* gc0  = (const float*)d_in[5];
    const float* bc0  = (const float*)d_in[6];
    const float* W1   = (const float*)d_in[7];
    const float* b1   = (const float*)d_in[8];
    const float* g1   = (const float*)d_in[9];
    const float* bg1  = (const float*)d_in[10];
    const float* gc1  = (const float*)d_in[11];
    const float* bc1  = (const float*)d_in[12];
    const float* WS   = (const float*)d_in[13];
    const float* bS   = (const float*)d_in[14];
    const float* gS   = (const float*)d_in[15];
    const float* bgS  = (const float*)d_in[16];
    const float* gcS  = (const float*)d_in[17];
    const float* bcS  = (const float*)d_in[18];
    const float* Wout = (const float*)d_in[19];
    const float* bout = (const float*)d_in[20];

    // ---- ws: states + z + hist + Wtout + flags (~34.9 MB, known-safe)
    float* ws = (float*)d_ws;
    float* fh = ws;
    float* fc = fh + B_ * F_;
    float* sh = fc + B_ * F_;
    float* sc = sh + B_ * S_;
    float* z  = sc + B_ * S_;
    u16* hist = (u16*)(z + (size_t)B_ * 4 * F_);
    u16* Wtout = hist + (size_t)12800 * FP_;
    unsigned* flags = (unsigned*)(Wtout + (size_t)10112 * FP_);

    // ---- d_out scratch (fully rewritten every call; dead before ogemm)
    const size_t P0 = (size_t)2816 * 832;
    const size_t PS = (size_t)1664 * 1120;
    const size_t P1 = (size_t)2816 * 1120;
    const size_t HF = (size_t)B_ * FP_;
    const size_t HS = (size_t)B_ * SP_;
    u16* dp  = (u16*)d_out;
    u16* W0H = dp;          u16* W0M = W0H + P0;  u16* W0L = W0M + P0;
    u16* WSH = W0L + P0;    u16* WSM = WSH + PS;  u16* WSL = WSM + PS;
    u16* W1H = WSL + PS;    u16* W1M = W1H + P1;  u16* W1L = W1M + P1;
    u16* fhH = W1L + P1;    u16* fhM = fhH + HF;  u16* fhL = fhM + HF;
    u16* shH = fhL + HF;    u16* shM = shH + HS;  u16* shL = shM + HS;
    float* zx = (float*)(shL + HS);

    hipMemsetAsync(flags, 0, (G_ * 16 + 16) * sizeof(unsigned), stream);
    hipMemsetAsync(fh, 0, (size_t)(2 * B_ * F_ + 2 * B_ * S_) * sizeof(float), stream);
    hipMemsetAsync(fhH, 0, (3 * HF + 3 * HS) * sizeof(u16), stream);

    wtrans3<<<dim3(88, 26), 256, 0, stream>>>(W0, E_ + F_, 4 * F_, W0H, W0M, W0L, 832, 128, 128);
    wtrans3<<<dim3(52, 35), 256, 0, stream>>>(WS, F_ + S_, 4 * S_, WSH, WSM, WSL, 1120, F_, FP_);
    wtrans3<<<dim3(88, 35), 256, 0, stream>>>(W1, S_ + F_, 4 * F_, W1H, W1M, W1L, 1120, S_, SP_);
    wtrans<<<dim3(316, 22), 256, 0, stream>>>(Wout, F_, V_, Wtout, FP_);

    zxpre<<<2188, 512, 0, stream>>>(inputs, W0H, W0M, W0L, b0, zx);

    hipFuncSetAttribute((const void*)mega,
                        hipFuncAttributeMaxDynamicSharedMemorySize, LDS_BYTES);

    mega<<<G_, TPB_, LDS_BYTES, stream>>>(
        b0, g0, bg0, gc0, bc0,
        b1, g1, bg1, gc1, bc1,
        bS, gS, bgS, gcS, bcS,
        zx,
        fh, fc, sh, sc, z, hist,
        fhH, fhM, fhL, shH, shM, shL,
        W0H, W0M, W0L, WSH, WSM, WSL, W1H, W1M, W1L,
        (float*)d_out + (size_t)B_ * T_ * V_, flags);

    ogemm<<<dim3(79, 50), 512, 0, stream>>>(hist, Wtout, bout, (float*)d_out);
}